// Round 3
// baseline (804.995 us; speedup 1.0000x reference)
//
#include <hip/hip_runtime.h>
#include <hip/hip_bf16.h>

#define E   384
#define Hd  512
#define KS  384
#define AHd 64
#define NK  6
#define BQ  64

typedef short bf16x8 __attribute__((ext_vector_type(8)));
typedef float f32x16 __attribute__((ext_vector_type(16)));
typedef unsigned int uint32;

#define MFMA32(A, B, C) __builtin_amdgcn_mfma_f32_32x32x16_bf16((A), (B), (C), 0, 0, 0)
#define Z16 {0.f,0.f,0.f,0.f,0.f,0.f,0.f,0.f,0.f,0.f,0.f,0.f,0.f,0.f,0.f,0.f}

__device__ __forceinline__ unsigned short f2bf(float f) {
    union { float f; unsigned int u; } c; c.f = f;
    unsigned int u = c.u;
    unsigned int r = (u + 0x7fffu + ((u >> 16) & 1u)) >> 16;   // RNE
    return (unsigned short)r;
}

__device__ __forceinline__ uint32 pk2(float a, float b) {
    return (uint32)f2bf(a) | ((uint32)f2bf(b) << 16);
}

union U8 { bf16x8 v; uint32 u[4]; };

// Convert 16 fp32 D-layout values (row=(r&3)+8*(r>>2)+4*hh over a 32-col tile)
// into two B-layout bf16 fragments (k_off 0..15 and 16..31) via pair-lane
// exchange with lane^32.
__device__ __forceinline__ void exch_pack(const float* t, int hh, bf16x8& fa, bf16x8& fb) {
    uint32 g0 = pk2(t[0],  t[1]),  g1 = pk2(t[2],  t[3]);
    uint32 g2 = pk2(t[4],  t[5]),  g3 = pk2(t[6],  t[7]);
    uint32 g4 = pk2(t[8],  t[9]),  g5 = pk2(t[10], t[11]);
    uint32 g6 = pk2(t[12], t[13]), g7 = pk2(t[14], t[15]);
    uint32 x0 = __shfl_xor(hh ? g0 : g2, 32, 64);
    uint32 x1 = __shfl_xor(hh ? g1 : g3, 32, 64);
    uint32 y0 = __shfl_xor(hh ? g4 : g6, 32, 64);
    uint32 y1 = __shfl_xor(hh ? g5 : g7, 32, 64);
    U8 A, B;
    A.u[0] = hh ? x0 : g0; A.u[1] = hh ? x1 : g1;
    A.u[2] = hh ? g2 : x0; A.u[3] = hh ? g3 : x1;
    B.u[0] = hh ? y0 : g4; B.u[1] = hh ? y1 : g5;
    B.u[2] = hh ? g6 : y0; B.u[3] = hh ? g7 : y1;
    fa = A.v; fb = B.v;
}

// ---------------------------------------------------------------------------
// Query prep, parallel fp32 (tiny work: ~25 M MAC total).
// ---------------------------------------------------------------------------
__global__ __launch_bounds__(256) void qh_kernel(
    const float* __restrict__ q, const float* __restrict__ W1,
    const float* __restrict__ b1, float* __restrict__ h)
{
    __shared__ float x[E];
    const int b = blockIdx.y;
    const int j = blockIdx.x * 256 + threadIdx.x;
    for (int i = threadIdx.x; i < E; i += 256) x[i] = q[b * E + i];
    __syncthreads();
    float acc = b1[j];
    #pragma unroll 4
    for (int i = 0; i < E; ++i) acc = fmaf(x[i], W1[i * Hd + j], acc);
    h[b * Hd + j] = fmaxf(acc, 0.f);
}

__global__ __launch_bounds__(64) void qah_kernel(
    const float* __restrict__ q, const float* __restrict__ Wa1,
    const float* __restrict__ ba1, float* __restrict__ ah)
{
    __shared__ float x[E];
    const int b = blockIdx.x, t = threadIdx.x;
    for (int i = t; i < E; i += 64) x[i] = q[b * E + i];
    __syncthreads();
    float acc = ba1[t];
    #pragma unroll 4
    for (int i = 0; i < E; ++i) acc = fmaf(x[i], Wa1[i * AHd + t], acc);
    ah[b * AHd + t] = fmaxf(acc, 0.f);
}

__global__ __launch_bounds__(384) void qfin_kernel(
    const float* __restrict__ h, const float* __restrict__ ah,
    const float* __restrict__ W2, const float* __restrict__ b2,
    const float* __restrict__ Wa2, const float* __restrict__ ba2,
    unsigned short* __restrict__ qw16)
{
    __shared__ float hl[Hd];
    __shared__ float al[AHd];
    __shared__ float lg[8];
    __shared__ float alpha[8];
    const int b = blockIdx.x, t = threadIdx.x;
    for (int i = t; i < Hd; i += 384) hl[i] = h[b * Hd + i];
    if (t < AHd) al[t] = ah[b * AHd + t];
    __syncthreads();
    float acc = b2[t];
    #pragma unroll 4
    for (int j = 0; j < Hd; ++j) acc = fmaf(hl[j], W2[j * KS + t], acc);
    // per-slot sumsq: wave w (t>>6) == slot (t>>6) since m == t
    float ss = acc * acc;
    #pragma unroll
    for (int d = 1; d < 64; d <<= 1) ss += __shfl_xor(ss, d, 64);
    float ninv = rsqrtf(ss + 1e-12f);
    if (t < NK) {
        float g = ba2[t];
        #pragma unroll 4
        for (int i = 0; i < AHd; ++i) g = fmaf(al[i], Wa2[i * NK + t], g);
        lg[t] = g;
    }
    __syncthreads();
    if (t == 0) {
        float mx = lg[0];
        for (int k = 1; k < NK; ++k) mx = fmaxf(mx, lg[k]);
        float s = 0.f, e[NK];
        for (int k = 0; k < NK; ++k) { e[k] = expf(lg[k] - mx); s += e[k]; }
        for (int k = 0; k < NK; ++k) alpha[k] = e[k] / s;
    }
    __syncthreads();
    qw16[b * KS + t] = f2bf(alpha[t >> 6] * ninv * acc);
}

// ---------------------------------------------------------------------------
// Pack weights into 32x32x16 MFMA fragments (B-layout for W1/W2, A-layout
// for qw), with bias folded in as an augmented K-row.
// W1p frag f = nt*25+kt (nt<16 over Hd cols, kt<25 over E=384+aug16)
// W2p frag f = nt*33+kt (nt<12 over KS cols, kt<33 over Hd=512+aug16)
// qwp frag f = qt*24+kt (qt<2 over 64 queries, kt<24 over KS)
// ---------------------------------------------------------------------------
__global__ __launch_bounds__(64) void pack_kernel(
    const float* __restrict__ W1, const float* __restrict__ b1,
    const float* __restrict__ W2, const float* __restrict__ b2,
    const unsigned short* __restrict__ qw16,
    unsigned short* __restrict__ W1p, unsigned short* __restrict__ W2p,
    unsigned short* __restrict__ qwp)
{
    const int f = blockIdx.x;
    const int l = threadIdx.x;
    const int n32 = l & 31, c = l >> 5;
    if (f < 400) {
        int nt = f / 25, kt = f % 25;
        unsigned short* dst = W1p + (size_t)f * 512 + l * 8;
        if (kt < 24) {
            int k0 = kt * 16 + c * 8, n = nt * 32 + n32;
            #pragma unroll
            for (int j = 0; j < 8; ++j) dst[j] = f2bf(W1[(size_t)(k0 + j) * Hd + n]);
        } else {
            #pragma unroll
            for (int j = 0; j < 8; ++j)
                dst[j] = (c == 0 && j == 0) ? f2bf(b1[nt * 32 + n32]) : 0;
        }
    } else if (f < 796) {
        int g = f - 400, nt = g / 33, kt = g % 33;
        unsigned short* dst = W2p + (size_t)g * 512 + l * 8;
        if (kt < 32) {
            int k0 = kt * 16 + c * 8, n = nt * 32 + n32;
            #pragma unroll
            for (int j = 0; j < 8; ++j) dst[j] = f2bf(W2[(size_t)(k0 + j) * KS + n]);
        } else {
            #pragma unroll
            for (int j = 0; j < 8; ++j)
                dst[j] = (c == 0 && j == 0) ? f2bf(b2[nt * 32 + n32]) : 0;
        }
    } else {
        int g = f - 796, qt = g / 24, kt = g % 24;
        unsigned short* dst = qwp + (size_t)g * 512 + l * 8;
        const unsigned short* src = qw16 + (size_t)(qt * 32 + n32) * KS + kt * 16 + c * 8;
        #pragma unroll
        for (int j = 0; j < 8; ++j) dst[j] = src[j];
    }
}

// ---------------------------------------------------------------------------
// Fused doc encode + score. 4 waves/block, 32 docs/wave (M=32), 32x32x16 MFMA.
// Fully register-resident: GEMM1/GEMM2 computed transposed (doc index in
// lanes), D-layout -> B-layout via shfl_xor(32) pair exchange. Epilogue
// through a 32KB LDS tile for fully-coalesced 512B-per-row stores.
// ---------------------------------------------------------------------------
__global__ __launch_bounds__(256, 2) void docscore3(
    const float* __restrict__ doc,
    const unsigned short* __restrict__ W1p,
    const unsigned short* __restrict__ W2p,
    const unsigned short* __restrict__ qwp,
    float* __restrict__ out, int Pd)
{
    __shared__ float outl[BQ * 128];   // 32 KB
    const int tid  = threadIdx.x;
    const int wave = tid >> 6, l = tid & 63;
    const int m = l & 31, hh = l >> 5;
    const int p0 = blockIdx.x * 128 + wave * 32;
    const size_t row = (size_t)min(p0 + m, Pd - 1);

    const bf16x8* W1f = (const bf16x8*)W1p;
    const bf16x8* W2f = (const bf16x8*)W2p;
    const bf16x8* qwf = (const bf16x8*)qwp;

    // ---- doc A-frags (as MFMA B operand): lane = m + 32*(k/8) ----
    bf16x8 xf[24];
    {
        const float* src = doc + row * E + hh * 8;
        #pragma unroll
        for (int kt = 0; kt < 24; ++kt) {
            float4 a = *(const float4*)(src + kt * 16);
            float4 b = *(const float4*)(src + kt * 16 + 4);
            bf16x8 v;
            v[0] = (short)f2bf(a.x); v[1] = (short)f2bf(a.y);
            v[2] = (short)f2bf(a.z); v[3] = (short)f2bf(a.w);
            v[4] = (short)f2bf(b.x); v[5] = (short)f2bf(b.y);
            v[6] = (short)f2bf(b.z); v[7] = (short)f2bf(b.w);
            xf[kt] = v;
        }
    }
    // augmented "1.0" K-row fragment (bias trick): k=aug_base -> 1.0
    bf16x8 aug = {0, 0, 0, 0, 0, 0, 0, 0};
    if (hh == 0) aug[0] = (short)0x3f80;

    // ---- GEMM1 (transposed): D[n][m] = sum_k W1[k][n] X[m][k] + b1[n] ----
    bf16x8 h2[32];
    #pragma unroll
    for (int nt = 0; nt < 16; ++nt) {
        const bf16x8* bp = W1f + (size_t)(nt * 25) * 64 + l;
        f32x16 a0 = Z16;
        #pragma unroll
        for (int kt = 0; kt < 24; ++kt)
            a0 = MFMA32(bp[(size_t)kt * 64], xf[kt], a0);
        a0 = MFMA32(bp[(size_t)24 * 64], aug, a0);
        float t[16];
        #pragma unroll
        for (int r = 0; r < 16; ++r) t[r] = fmaxf(a0[r], 0.f);
        exch_pack(t, hh, h2[2 * nt], h2[2 * nt + 1]);
    }

    // ---- GEMM2 (transposed) + per-slot L2 norm, slot = pair of 32-col tiles
    bf16x8 s3[24];
    #pragma unroll
    for (int np = 0; np < 6; ++np) {
        float t0[16], t1[16];
        {
            const bf16x8* bp = W2f + (size_t)((2 * np) * 33) * 64 + l;
            f32x16 a0 = Z16;
            #pragma unroll
            for (int kt = 0; kt < 32; ++kt)
                a0 = MFMA32(bp[(size_t)kt * 64], h2[kt], a0);
            a0 = MFMA32(bp[(size_t)32 * 64], aug, a0);
            #pragma unroll
            for (int r = 0; r < 16; ++r) t0[r] = a0[r];
        }
        {
            const bf16x8* bp = W2f + (size_t)((2 * np + 1) * 33) * 64 + l;
            f32x16 a0 = Z16;
            #pragma unroll
            for (int kt = 0; kt < 32; ++kt)
                a0 = MFMA32(bp[(size_t)kt * 64], h2[kt], a0);
            a0 = MFMA32(bp[(size_t)32 * 64], aug, a0);
            #pragma unroll
            for (int r = 0; r < 16; ++r) t1[r] = a0[r];
        }
        float ss = 0.f;
        #pragma unroll
        for (int r = 0; r < 16; ++r) ss += t0[r] * t0[r] + t1[r] * t1[r];
        ss += __shfl_xor(ss, 32, 64);
        float ninv = rsqrtf(ss + 1e-12f);
        #pragma unroll
        for (int r = 0; r < 16; ++r) { t0[r] *= ninv; t1[r] *= ninv; }
        exch_pack(t0, hh, s3[4 * np],     s3[4 * np + 1]);
        exch_pack(t1, hh, s3[4 * np + 2], s3[4 * np + 3]);
    }

    // ---- GEMM3: D[q][doc] = qw . s_hat ----
    #pragma unroll
    for (int qt = 0; qt < 2; ++qt) {
        const bf16x8* bp = qwf + (size_t)(qt * 24) * 64 + l;
        f32x16 a0 = Z16;
        #pragma unroll
        for (int kt = 0; kt < 24; ++kt)
            a0 = MFMA32(bp[(size_t)kt * 64], s3[kt], a0);
        #pragma unroll
        for (int r = 0; r < 16; ++r) {
            int qq = qt * 32 + (r & 3) + 8 * (r >> 2) + 4 * hh;
            outl[qq * 128 + wave * 32 + m] = a0[r];
        }
    }
    __syncthreads();

    // ---- coalesced store: 64 q-rows x 128 docs ----
    {
        const int pblk = blockIdx.x * 128;
        #pragma unroll
        for (int i = 0; i < 8; ++i) {
            int qq = i * 8 + (tid >> 5);
            int c  = (tid & 31) * 4;
            float4 v = *(const float4*)&outl[qq * 128 + c];
            int p = pblk + c;
            float* op = out + (size_t)qq * Pd + p;
            if (p + 3 < Pd) {
                *(float4*)op = v;
            } else {
                float vv[4] = {v.x, v.y, v.z, v.w};
                for (int jj = 0; jj < 4; ++jj)
                    if (p + jj < Pd) op[jj] = vv[jj];
            }
        }
    }
}

extern "C" void kernel_launch(void* const* d_in, const int* in_sizes, int n_in,
                              void* d_out, int out_size, void* d_ws, size_t ws_size,
                              hipStream_t stream) {
    const float* qe  = (const float*)d_in[0];
    const float* de  = (const float*)d_in[1];
    const float* W1  = (const float*)d_in[2];
    const float* b1  = (const float*)d_in[3];
    const float* W2  = (const float*)d_in[4];
    const float* b2  = (const float*)d_in[5];
    const float* Wa1 = (const float*)d_in[6];
    const float* ba1 = (const float*)d_in[7];
    const float* Wa2 = (const float*)d_in[8];
    const float* ba2 = (const float*)d_in[9];
    float* out = (float*)d_out;

    // ws layout (913408 B total; W1p region reuses h/ah after qfin):
    unsigned short* qw16 = (unsigned short*)d_ws;                          //  49152 B
    float*          h    = (float*)((char*)d_ws + 49152);                  // 131072 B (phase 1)
    float*          ah   = (float*)((char*)d_ws + 180224);                 //  16384 B (phase 1)
    unsigned short* W1p  = (unsigned short*)((char*)d_ws + 49152);         // 409600 B (phase 2+)
    unsigned short* W2p  = (unsigned short*)((char*)d_ws + 458752);        // 405504 B
    unsigned short* qwp  = (unsigned short*)((char*)d_ws + 864256);        //  49152 B

    const int Pd = in_sizes[1] / E;   // 100000

    qh_kernel<<<dim3(2, BQ), 256, 0, stream>>>(qe, W1, b1, h);
    qah_kernel<<<BQ, 64, 0, stream>>>(qe, Wa1, ba1, ah);
    qfin_kernel<<<BQ, 384, 0, stream>>>(h, ah, W2, b2, Wa2, ba2, qw16);
    pack_kernel<<<844, 64, 0, stream>>>(W1, b1, W2, b2, qw16, W1p, W2p, qwp);

    const int nblk = (Pd + 127) / 128;
    docscore3<<<nblk, 256, 0, stream>>>(de, W1p, W2p, qwp, out, Pd);
}

// Round 4
// 593.277 us; speedup vs baseline: 1.3569x; 1.3569x over previous
//
#include <hip/hip_runtime.h>
#include <hip/hip_bf16.h>

#define E   384
#define Hd  512
#define KS  384
#define AHd 64
#define NK  6
#define BQ  64

typedef short bf16x8 __attribute__((ext_vector_type(8)));
typedef float f32x16 __attribute__((ext_vector_type(16)));
typedef unsigned int uint32;

#define MFMA32(A, B, C) __builtin_amdgcn_mfma_f32_32x32x16_bf16((A), (B), (C), 0, 0, 0)
#define Z16 {0.f,0.f,0.f,0.f,0.f,0.f,0.f,0.f,0.f,0.f,0.f,0.f,0.f,0.f,0.f,0.f}

__device__ __forceinline__ unsigned short f2bf(float f) {
    union { float f; unsigned int u; } c; c.f = f;
    unsigned int u = c.u;
    unsigned int r = (u + 0x7fffu + ((u >> 16) & 1u)) >> 16;   // RNE
    return (unsigned short)r;
}

__device__ __forceinline__ uint32 pk2(float a, float b) {
    return (uint32)f2bf(a) | ((uint32)f2bf(b) << 16);
}

union U8 { bf16x8 v; uint32 u[4]; };

// D-layout (row=(r&3)+8*(r>>2)+4*hh over a 32-col tile) -> two B-layout bf16
// fragments via pair-lane exchange with lane^32.  [verified round 3]
__device__ __forceinline__ void exch_pack(const float* t, int hh, bf16x8& fa, bf16x8& fb) {
    uint32 g0 = pk2(t[0],  t[1]),  g1 = pk2(t[2],  t[3]);
    uint32 g2 = pk2(t[4],  t[5]),  g3 = pk2(t[6],  t[7]);
    uint32 g4 = pk2(t[8],  t[9]),  g5 = pk2(t[10], t[11]);
    uint32 g6 = pk2(t[12], t[13]), g7 = pk2(t[14], t[15]);
    uint32 x0 = __shfl_xor(hh ? g0 : g2, 32, 64);
    uint32 x1 = __shfl_xor(hh ? g1 : g3, 32, 64);
    uint32 y0 = __shfl_xor(hh ? g4 : g6, 32, 64);
    uint32 y1 = __shfl_xor(hh ? g5 : g7, 32, 64);
    U8 A, B;
    A.u[0] = hh ? x0 : g0; A.u[1] = hh ? x1 : g1;
    A.u[2] = hh ? g2 : x0; A.u[3] = hh ? g3 : x1;
    B.u[0] = hh ? y0 : g4; B.u[1] = hh ? y1 : g5;
    B.u[2] = hh ? g6 : y0; B.u[3] = hh ? g7 : y1;
    fa = A.v; fb = B.v;
}

// ---------------------------------------------------------------------------
// Query prep (unchanged from round 3 — known correct).
// ---------------------------------------------------------------------------
__global__ __launch_bounds__(256) void qh_kernel(
    const float* __restrict__ q, const float* __restrict__ W1,
    const float* __restrict__ b1, float* __restrict__ h)
{
    __shared__ float x[E];
    const int b = blockIdx.y;
    const int j = blockIdx.x * 256 + threadIdx.x;
    for (int i = threadIdx.x; i < E; i += 256) x[i] = q[b * E + i];
    __syncthreads();
    float acc = b1[j];
    #pragma unroll 4
    for (int i = 0; i < E; ++i) acc = fmaf(x[i], W1[i * Hd + j], acc);
    h[b * Hd + j] = fmaxf(acc, 0.f);
}

__global__ __launch_bounds__(64) void qah_kernel(
    const float* __restrict__ q, const float* __restrict__ Wa1,
    const float* __restrict__ ba1, float* __restrict__ ah)
{
    __shared__ float x[E];
    const int b = blockIdx.x, t = threadIdx.x;
    for (int i = t; i < E; i += 64) x[i] = q[b * E + i];
    __syncthreads();
    float acc = ba1[t];
    #pragma unroll 4
    for (int i = 0; i < E; ++i) acc = fmaf(x[i], Wa1[i * AHd + t], acc);
    ah[b * AHd + t] = fmaxf(acc, 0.f);
}

__global__ __launch_bounds__(384) void qfin_kernel(
    const float* __restrict__ h, const float* __restrict__ ah,
    const float* __restrict__ W2, const float* __restrict__ b2,
    const float* __restrict__ Wa2, const float* __restrict__ ba2,
    unsigned short* __restrict__ qw16)
{
    __shared__ float hl[Hd];
    __shared__ float al[AHd];
    __shared__ float lg[8];
    __shared__ float alpha[8];
    const int b = blockIdx.x, t = threadIdx.x;
    for (int i = t; i < Hd; i += 384) hl[i] = h[b * Hd + i];
    if (t < AHd) al[t] = ah[b * AHd + t];
    __syncthreads();
    float acc = b2[t];
    #pragma unroll 4
    for (int j = 0; j < Hd; ++j) acc = fmaf(hl[j], W2[j * KS + t], acc);
    float ss = acc * acc;
    #pragma unroll
    for (int d = 1; d < 64; d <<= 1) ss += __shfl_xor(ss, d, 64);
    float ninv = rsqrtf(ss + 1e-12f);
    if (t < NK) {
        float g = ba2[t];
        #pragma unroll 4
        for (int i = 0; i < AHd; ++i) g = fmaf(al[i], Wa2[i * NK + t], g);
        lg[t] = g;
    }
    __syncthreads();
    if (t == 0) {
        float mx = lg[0];
        for (int k = 1; k < NK; ++k) mx = fmaxf(mx, lg[k]);
        float s = 0.f, e[NK];
        for (int k = 0; k < NK; ++k) { e[k] = expf(lg[k] - mx); s += e[k]; }
        for (int k = 0; k < NK; ++k) alpha[k] = e[k] / s;
    }
    __syncthreads();
    qw16[b * KS + t] = f2bf(alpha[t >> 6] * ninv * acc);
}

// ---------------------------------------------------------------------------
// Pack weights into 32x32x16 MFMA fragments (unchanged from round 3).
// W1p frag f = nt*25+kt (nt<16, kt<25 incl aug) ; W2p f = nt*33+kt (nt<12,
// kt<33 incl aug) ; qwp f = qt*24+kt (qt<2, kt<24).
// ---------------------------------------------------------------------------
__global__ __launch_bounds__(64) void pack_kernel(
    const float* __restrict__ W1, const float* __restrict__ b1,
    const float* __restrict__ W2, const float* __restrict__ b2,
    const unsigned short* __restrict__ qw16,
    unsigned short* __restrict__ W1p, unsigned short* __restrict__ W2p,
    unsigned short* __restrict__ qwp)
{
    const int f = blockIdx.x;
    const int l = threadIdx.x;
    const int n32 = l & 31, c = l >> 5;
    if (f < 400) {
        int nt = f / 25, kt = f % 25;
        unsigned short* dst = W1p + (size_t)f * 512 + l * 8;
        if (kt < 24) {
            int k0 = kt * 16 + c * 8, n = nt * 32 + n32;
            #pragma unroll
            for (int j = 0; j < 8; ++j) dst[j] = f2bf(W1[(size_t)(k0 + j) * Hd + n]);
        } else {
            #pragma unroll
            for (int j = 0; j < 8; ++j)
                dst[j] = (c == 0 && j == 0) ? f2bf(b1[nt * 32 + n32]) : 0;
        }
    } else if (f < 796) {
        int g = f - 400, nt = g / 33, kt = g % 33;
        unsigned short* dst = W2p + (size_t)g * 512 + l * 8;
        if (kt < 32) {
            int k0 = kt * 16 + c * 8, n = nt * 32 + n32;
            #pragma unroll
            for (int j = 0; j < 8; ++j) dst[j] = f2bf(W2[(size_t)(k0 + j) * KS + n]);
        } else {
            #pragma unroll
            for (int j = 0; j < 8; ++j)
                dst[j] = (c == 0 && j == 0) ? f2bf(b2[nt * 32 + n32]) : 0;
        }
    } else {
        int g = f - 796, qt = g / 24, kt = g % 24;
        unsigned short* dst = qwp + (size_t)g * 512 + l * 8;
        const unsigned short* src = qw16 + (size_t)(qt * 32 + n32) * KS + kt * 16 + c * 8;
        #pragma unroll
        for (int j = 0; j < 8; ++j) dst[j] = src[j];
    }
}

// ---------------------------------------------------------------------------
// Chunk staging helpers: 256 threads copy NF 1-KB fragments global->regs and
// regs->LDS (register-mediated double buffer; global latency hidden by the
// MFMA compute between ldc and stc).
// ---------------------------------------------------------------------------
template<int NF>
__device__ __forceinline__ void ldc(const bf16x8* __restrict__ g, bf16x8* r, int tid) {
    constexpr int TOT = NF * 64;              // 16B units
    constexpr int R = (TOT + 255) / 256;
    #pragma unroll
    for (int i = 0; i < R; ++i) {
        int off = i * 256 + tid;
        if ((TOT % 256 == 0) || off < TOT) r[i] = g[off];
    }
}
template<int NF>
__device__ __forceinline__ void stc(short* b, const bf16x8* r, int tid) {
    constexpr int TOT = NF * 64;
    constexpr int R = (TOT + 255) / 256;
    #pragma unroll
    for (int i = 0; i < R; ++i) {
        int off = i * 256 + tid;
        if ((TOT % 256 == 0) || off < TOT) *(bf16x8*)&b[off * 8] = r[i];
    }
}

// ---------------------------------------------------------------------------
// Fused doc encode + score. 4 waves/block, 32 docs/wave (M=128/block).
// Weights staged through LDS once per block (shared by all 4 waves); chunked
// double-buffered stream; 2 accumulator chains per tile; 512-VGPR budget.
// ---------------------------------------------------------------------------
__global__ __launch_bounds__(256, 1) void docscore4(
    const float* __restrict__ doc,
    const unsigned short* __restrict__ W1p,
    const unsigned short* __restrict__ W2p,
    const unsigned short* __restrict__ qwp,
    float* __restrict__ out, int Pd)
{
    __shared__ short wbuf[2][17 * 512];       // 2 x 17 KB chunk buffers
    __shared__ float outl[32 * 128];          // 16 KB epilogue tile

    const int tid  = threadIdx.x;
    const int wave = tid >> 6, l = tid & 63;
    const int m = l & 31, hh = l >> 5;
    const int p0 = blockIdx.x * 128 + wave * 32;
    const size_t row = (size_t)min(p0 + m, Pd - 1);

    const bf16x8* W1f = (const bf16x8*)W1p;
    const bf16x8* W2f = (const bf16x8*)W2p;
    const bf16x8* qwf = (const bf16x8*)qwp;
    short* buf0 = wbuf[0];
    short* buf1 = wbuf[1];

    // ---- doc fragments (B operand): lane m = doc, k = kt*16 + hh*8 + j ----
    bf16x8 xf[24];
    {
        const float* src = doc + row * E + hh * 8;
        #pragma unroll
        for (int kt = 0; kt < 24; ++kt) {
            float4 a = *(const float4*)(src + kt * 16);
            float4 b = *(const float4*)(src + kt * 16 + 4);
            bf16x8 v;
            v[0] = (short)f2bf(a.x); v[1] = (short)f2bf(a.y);
            v[2] = (short)f2bf(a.z); v[3] = (short)f2bf(a.w);
            v[4] = (short)f2bf(b.x); v[5] = (short)f2bf(b.y);
            v[6] = (short)f2bf(b.z); v[7] = (short)f2bf(b.w);
            xf[kt] = v;
        }
    }
    bf16x8 aug = {0, 0, 0, 0, 0, 0, 0, 0};
    if (hh == 0) aug[0] = (short)0x3f80;      // 1.0 at local k=0 (bias row)

    bf16x8 pre[5];

    // ---- prologue: stage GEMM1 chunk (nt=0, A) ----
    ldc<16>(W1f, pre, tid);
    stc<16>(buf0, pre, tid);
    __syncthreads();

    // ---- Phase 1: H = relu(X@W1 + b1), transposed D[n][doc] ----
    bf16x8 h2[32];
    #pragma unroll
    for (int nt = 0; nt < 16; ++nt) {
        ldc<12>(W1f + (size_t)(nt * 25 + 13) * 64, pre, tid);
        f32x16 acc0 = Z16, acc1 = Z16;
        #pragma unroll
        for (int j = 0; j < 13; ++j) {
            bf16x8 wf = *(const bf16x8*)&buf0[j * 512 + l * 8];
            if (j < 7) acc0 = MFMA32(wf, xf[j], acc0);
            else       acc1 = MFMA32(wf, xf[j], acc1);
        }
        stc<12>(buf1, pre, tid);
        __syncthreads();
        if (nt < 15) ldc<16>(W1f + (size_t)((nt + 1) * 25) * 64, pre, tid);
        else         ldc<16>(W2f, pre, tid);
        #pragma unroll
        for (int j = 0; j < 12; ++j) {
            bf16x8 wf = *(const bf16x8*)&buf1[j * 512 + l * 8];
            bf16x8 bop = (j < 11) ? xf[13 + j] : aug;
            if (j < 6) acc0 = MFMA32(wf, bop, acc0);
            else       acc1 = MFMA32(wf, bop, acc1);
        }
        stc<16>(buf0, pre, tid);
        __syncthreads();
        float t[16];
        #pragma unroll
        for (int r = 0; r < 16; ++r) t[r] = fmaxf(acc0[r] + acc1[r], 0.f);
        exch_pack(t, hh, h2[2 * nt], h2[2 * nt + 1]);
    }

    // ---- Phase 2: S = H@W2 + b2, per-slot L2 norm (slot = 2 nt tiles) ----
    bf16x8 s3[24];
    #pragma unroll
    for (int np = 0; np < 6; ++np) {
        float t0[16], t1[16];
        #pragma unroll
        for (int half = 0; half < 2; ++half) {
            const int nt = 2 * np + half;
            ldc<17>(W2f + (size_t)(nt * 33 + 16) * 64, pre, tid);
            f32x16 acc0 = Z16, acc1 = Z16;
            #pragma unroll
            for (int j = 0; j < 16; ++j) {
                bf16x8 wf = *(const bf16x8*)&buf0[j * 512 + l * 8];
                if (j < 8) acc0 = MFMA32(wf, h2[j], acc0);
                else       acc1 = MFMA32(wf, h2[j], acc1);
            }
            stc<17>(buf1, pre, tid);
            __syncthreads();
            if (nt < 11) ldc<16>(W2f + (size_t)((nt + 1) * 33) * 64, pre, tid);
            else         ldc<16>(qwf, pre, tid);
            #pragma unroll
            for (int j = 0; j < 17; ++j) {
                bf16x8 wf = *(const bf16x8*)&buf1[j * 512 + l * 8];
                bf16x8 bop = (j < 16) ? h2[16 + j] : aug;
                if (j < 8) acc0 = MFMA32(wf, bop, acc0);
                else       acc1 = MFMA32(wf, bop, acc1);
            }
            stc<16>(buf0, pre, tid);
            __syncthreads();
            float* tt = half ? t1 : t0;
            #pragma unroll
            for (int r = 0; r < 16; ++r) tt[r] = acc0[r] + acc1[r];
        }
        float ss = 0.f;
        #pragma unroll
        for (int r = 0; r < 16; ++r) ss += t0[r] * t0[r] + t1[r] * t1[r];
        ss += __shfl_xor(ss, 32, 64);
        float ninv = rsqrtf(ss + 1e-12f);
        #pragma unroll
        for (int r = 0; r < 16; ++r) { t0[r] *= ninv; t1[r] *= ninv; }
        exch_pack(t0, hh, s3[4 * np],     s3[4 * np + 1]);
        exch_pack(t1, hh, s3[4 * np + 2], s3[4 * np + 3]);
    }

    // ---- Phase 3: scores D[q][doc] = qw . s_hat ----
    float qres[2][16];
    #pragma unroll
    for (int qt = 0; qt < 2; ++qt) {
        ldc<12>(qwf + (size_t)(qt * 24 + 12) * 64, pre, tid);
        f32x16 acc0 = Z16, acc1 = Z16;
        #pragma unroll
        for (int j = 0; j < 12; ++j) {
            bf16x8 wf = *(const bf16x8*)&buf0[j * 512 + l * 8];
            if (j < 6) acc0 = MFMA32(wf, s3[j], acc0);
            else       acc1 = MFMA32(wf, s3[j], acc1);
        }
        stc<12>(buf1, pre, tid);
        __syncthreads();
        if (qt == 0) ldc<12>(qwf + (size_t)24 * 64, pre, tid);
        #pragma unroll
        for (int j = 0; j < 12; ++j) {
            bf16x8 wf = *(const bf16x8*)&buf1[j * 512 + l * 8];
            if (j < 6) acc0 = MFMA32(wf, s3[12 + j], acc0);
            else       acc1 = MFMA32(wf, s3[12 + j], acc1);
        }
        if (qt == 0) stc<12>(buf0, pre, tid);
        __syncthreads();
        #pragma unroll
        for (int r = 0; r < 16; ++r) qres[qt][r] = acc0[r] + acc1[r];
    }

    // ---- epilogue: two 32-query rounds through LDS, coalesced stores ----
    const int pblk = blockIdx.x * 128;
    #pragma unroll
    for (int qt = 0; qt < 2; ++qt) {
        #pragma unroll
        for (int r = 0; r < 16; ++r) {
            int qq = (r & 3) + 8 * (r >> 2) + 4 * hh;
            outl[qq * 128 + wave * 32 + m] = qres[qt][r];
        }
        __syncthreads();
        #pragma unroll
        for (int i = 0; i < 4; ++i) {
            int rrow = i * 8 + (tid >> 5);
            int c = (tid & 31) * 4;
            float4 v = *(const float4*)&outl[rrow * 128 + c];
            int p = pblk + c;
            float* op = out + (size_t)(qt * 32 + rrow) * Pd + p;
            if (p + 3 < Pd) {
                *(float4*)op = v;
            } else {
                float vv[4] = {v.x, v.y, v.z, v.w};
                for (int jj = 0; jj < 4; ++jj)
                    if (p + jj < Pd) op[jj] = vv[jj];
            }
        }
        __syncthreads();
    }
}

extern "C" void kernel_launch(void* const* d_in, const int* in_sizes, int n_in,
                              void* d_out, int out_size, void* d_ws, size_t ws_size,
                              hipStream_t stream) {
    const float* qe  = (const float*)d_in[0];
    const float* de  = (const float*)d_in[1];
    const float* W1  = (const float*)d_in[2];
    const float* b1  = (const float*)d_in[3];
    const float* W2  = (const float*)d_in[4];
    const float* b2  = (const float*)d_in[5];
    const float* Wa1 = (const float*)d_in[6];
    const float* ba1 = (const float*)d_in[7];
    const float* Wa2 = (const float*)d_in[8];
    const float* ba2 = (const float*)d_in[9];
    float* out = (float*)d_out;

    // ws layout (W1p region reuses h/ah scratch after qfin):
    unsigned short* qw16 = (unsigned short*)d_ws;                          //  49152 B
    float*          h    = (float*)((char*)d_ws + 49152);                  // 131072 B (phase 1)
    float*          ah   = (float*)((char*)d_ws + 180224);                 //  16384 B (phase 1)
    unsigned short* W1p  = (unsigned short*)((char*)d_ws + 49152);         // 409600 B (phase 2+)
    unsigned short* W2p  = (unsigned short*)((char*)d_ws + 458752);        // 405504 B
    unsigned short* qwp  = (unsigned short*)((char*)d_ws + 864256);        //  49152 B

    const int Pd = in_sizes[1] / E;   // 100000

    qh_kernel<<<dim3(2, BQ), 256, 0, stream>>>(qe, W1, b1, h);
    qah_kernel<<<BQ, 64, 0, stream>>>(qe, Wa1, ba1, ah);
    qfin_kernel<<<BQ, 384, 0, stream>>>(h, ah, W2, b2, Wa2, ba2, qw16);
    pack_kernel<<<844, 64, 0, stream>>>(W1, b1, W2, b2, qw16, W1p, W2p, qwp);

    const int nblk = (Pd + 127) / 128;
    docscore4<<<nblk, 256, 0, stream>>>(de, W1p, W2p, qwp, out, Pd);
}